// Round 3
// baseline (171.250 us; speedup 1.0000x reference)
//
#include <hip/hip_runtime.h>

#define E_TOTAL  600000
#define N_NODES  100000
#define DFEAT    128
#define STEPS    8
#define EPB      (64 * STEPS)                       // edges per block = 512
#define NB       ((E_TOTAL + EPB - 1) / EPB)        // 1172

typedef __attribute__((ext_vector_type(8))) short  short8;
typedef __attribute__((ext_vector_type(4))) float  f32x4;

static __device__ __forceinline__ unsigned short f2bf(float f) {
    unsigned int u = __float_as_uint(f);
    unsigned int r = (u + 0x7fffu + ((u >> 16) & 1u)) >> 16;
    return (unsigned short)r;
}
static __device__ __forceinline__ float bf2f(unsigned short u) {
    unsigned int x = ((unsigned int)u) << 16;
    return __uint_as_float(x);
}

// w1abt[c][k], c in [0,256): c<128 -> W1[k][c] (src half); c>=128 -> W1[128+k][c-128] (dst half)
// w2t[c][k] = W2[k][c]
__global__ void prep_w_fast(const float* __restrict__ W1, const float* __restrict__ W2,
                            unsigned short* __restrict__ w1abt, unsigned short* __restrict__ w2t) {
    int i = blockIdx.x * blockDim.x + threadIdx.x;
    if (i < 256 * 128) {
        int c = i >> 7, k = i & 127;
        w1abt[i] = f2bf(W1[(k + (c & 128)) * 128 + (c & 127)]);
    } else {
        int j = i - 256 * 128;
        if (j < 64 * 128) {
            int c = j >> 7, k = j & 127;
            w2t[j] = f2bf(W2[k * 64 + c]);
        }
    }
}

// PQ[n][0:128] = enc[n] @ W1a + b1 ; PQ[n][128:256] = enc[n] @ W1b   (bf16)
__global__ __launch_bounds__(256, 2) void build_pq(
        const float* __restrict__ enc, const float* __restrict__ b1,
        const unsigned short* __restrict__ w1abt, unsigned short* __restrict__ PQ)
{
    __shared__ unsigned short sX[64 * 128];
    __shared__ unsigned short sOut[64 * 264];

    const int tid = threadIdx.x, lane = tid & 63, w = tid >> 6;
    const int acol = lane & 15, g = lane >> 4;
    const int n0 = blockIdx.x * 64;

    {
        int r = tid >> 2, q = tid & 3;
        int n = n0 + r; if (n >= N_NODES) n = N_NODES - 1;
        const float* src = enc + (size_t)n * DFEAT + q * 32;
#pragma unroll
        for (int i = 0; i < 4; ++i) {
            float4 v0 = *reinterpret_cast<const float4*>(src + i * 8);
            float4 v1 = *reinterpret_cast<const float4*>(src + i * 8 + 4);
            short8 pv;
            pv[0] = (short)f2bf(v0.x); pv[1] = (short)f2bf(v0.y);
            pv[2] = (short)f2bf(v0.z); pv[3] = (short)f2bf(v0.w);
            pv[4] = (short)f2bf(v1.x); pv[5] = (short)f2bf(v1.y);
            pv[6] = (short)f2bf(v1.z); pv[7] = (short)f2bf(v1.w);
            int chunk = (q * 4 + i) ^ (r & 7);
            *reinterpret_cast<short8*>(&sX[r * 128 + chunk * 8]) = pv;
        }
    }

    short8 bf[4][4];
#pragma unroll
    for (int ks = 0; ks < 4; ++ks)
#pragma unroll
        for (int ni = 0; ni < 4; ++ni) {
            int c = w * 64 + ni * 16 + acol;
            bf[ks][ni] = *reinterpret_cast<const short8*>(w1abt + c * 128 + ks * 32 + g * 8);
        }
    float b1v[4];
#pragma unroll
    for (int ni = 0; ni < 4; ++ni) {
        int c = w * 64 + ni * 16 + acol;
        b1v[ni] = (c < 128) ? b1[c] : 0.f;
    }
    __syncthreads();

    f32x4 acc[4][4];
#pragma unroll
    for (int mi = 0; mi < 4; ++mi)
#pragma unroll
        for (int ni = 0; ni < 4; ++ni)
            acc[mi][ni] = (f32x4){0.f, 0.f, 0.f, 0.f};

#pragma unroll
    for (int ks = 0; ks < 4; ++ks) {
        short8 a[4];
#pragma unroll
        for (int mi = 0; mi < 4; ++mi) {
            int r = mi * 16 + acol;
            a[mi] = *reinterpret_cast<const short8*>(&sX[r * 128 + (((ks * 4 + g) ^ (r & 7)) * 8)]);
        }
#pragma unroll
        for (int mi = 0; mi < 4; ++mi)
#pragma unroll
            for (int ni = 0; ni < 4; ++ni)
                acc[mi][ni] = __builtin_amdgcn_mfma_f32_16x16x32_bf16(a[mi], bf[ks][ni], acc[mi][ni], 0, 0, 0);
    }

#pragma unroll
    for (int mi = 0; mi < 4; ++mi)
#pragma unroll
        for (int ni = 0; ni < 4; ++ni)
#pragma unroll
            for (int rr = 0; rr < 4; ++rr) {
                int row = mi * 16 + g * 4 + rr;
                int col = w * 64 + ni * 16 + acol;
                sOut[row * 264 + col] = f2bf(acc[mi][ni][rr] + b1v[ni]);
            }
    __syncthreads();
    {
        int r = tid >> 2, q = tid & 3;
        int n = n0 + r;
        if (n < N_NODES) {
            unsigned short* dst = PQ + (size_t)n * 256 + q * 64;
#pragma unroll
            for (int i = 0; i < 8; ++i)
                *reinterpret_cast<short8*>(dst + i * 8) =
                    *reinterpret_cast<const short8*>(&sOut[r * 264 + q * 64 + i * 8]);
        }
    }
}

// ---------------- edge head, swapped-operand, barrier-free main loop ----------------

struct G8 { short8 p[4]; short8 q[4]; };

static __device__ __forceinline__ void gather_step(
        int E, const int* __restrict__ eidx, const unsigned short* __restrict__ PQ,
        int g, G8& r)
{
    int sn = eidx[E];
    int dn = eidx[E_TOTAL + E];
    const unsigned short* ps = PQ + (size_t)sn * 256 + g * 8;
    const unsigned short* pd = PQ + (size_t)dn * 256 + 128 + g * 8;
#pragma unroll
    for (int ks = 0; ks < 4; ++ks) {
        r.p[ks] = *reinterpret_cast<const short8*>(ps + ks * 32);
        r.q[ks] = *reinterpret_cast<const short8*>(pd + ks * 32);
    }
}

static __device__ __forceinline__ void compute_step(
        const G8& r, int E, bool valid,
        const unsigned short* __restrict__ sW2,
        const float* __restrict__ sB2, const float* __restrict__ sW3,
        int e16, int g, float b3v0, float b3v1,
        float* __restrict__ out)
{
    // B-fragments: h1[edge][k-slice] = relu(P+Q), lane-local
    short8 hb[4];
#pragma unroll
    for (int ks = 0; ks < 4; ++ks) {
#pragma unroll
        for (int j = 0; j < 8; ++j) {
            float v = bf2f((unsigned short)r.p[ks][j]) + bf2f((unsigned short)r.q[ks][j]);
            v = fmaxf(v, 0.f);
            hb[ks][j] = (short)f2bf(v);
        }
    }
    // h2^T tiles: D[ch][edge], each wave owns 16 edges x all 64 channels
    f32x4 acc[4];
#pragma unroll
    for (int t = 0; t < 4; ++t) acc[t] = (f32x4){0.f, 0.f, 0.f, 0.f};
#pragma unroll
    for (int ks = 0; ks < 4; ++ks) {
#pragma unroll
        for (int t = 0; t < 4; ++t) {
            int ch = t * 16 + e16;
            short8 a = *reinterpret_cast<const short8*>(
                &sW2[ch * 128 + (((ks * 4 + g) ^ (ch & 7)) * 8)]);
            acc[t] = __builtin_amdgcn_mfma_f32_16x16x32_bf16(a, hb[ks], acc[t], 0, 0, 0);
        }
    }
    // layer 3: lane holds ch = t*16 + g*4 + rr for its edge
    float lg0 = 0.f, lg1 = 0.f;
#pragma unroll
    for (int t = 0; t < 4; ++t) {
        int c0 = t * 16 + g * 4;
        float4 bb  = *reinterpret_cast<const float4*>(&sB2[c0]);
        float4 w30 = *reinterpret_cast<const float4*>(&sW3[c0 * 2]);
        float4 w31 = *reinterpret_cast<const float4*>(&sW3[c0 * 2 + 4]);
        float h0 = fmaxf(acc[t][0] + bb.x, 0.f);
        float h1 = fmaxf(acc[t][1] + bb.y, 0.f);
        float h2 = fmaxf(acc[t][2] + bb.z, 0.f);
        float h3 = fmaxf(acc[t][3] + bb.w, 0.f);
        lg0 = fmaf(h0, w30.x, lg0); lg1 = fmaf(h0, w30.y, lg1);
        lg0 = fmaf(h1, w30.z, lg0); lg1 = fmaf(h1, w30.w, lg1);
        lg0 = fmaf(h2, w31.x, lg0); lg1 = fmaf(h2, w31.y, lg1);
        lg0 = fmaf(h3, w31.z, lg0); lg1 = fmaf(h3, w31.w, lg1);
    }
    // reduce over the 4 k-groups (lanes e, e+16, e+32, e+48)
    lg0 += __shfl_xor(lg0, 16, 64); lg1 += __shfl_xor(lg1, 16, 64);
    lg0 += __shfl_xor(lg0, 32, 64); lg1 += __shfl_xor(lg1, 32, 64);
    if (g == 0 && valid) {
        lg0 += b3v0; lg1 += b3v1;
        float m = fmaxf(lg0, lg1);
        float lse = m + __logf(__expf(lg0 - m) + __expf(lg1 - m));
        *reinterpret_cast<float2*>(out + (size_t)E * 2) = make_float2(lg0 - lse, lg1 - lse);
    }
}

__global__ __launch_bounds__(256, 4) void edge_head2(
        const unsigned short* __restrict__ PQ,
        const int* __restrict__ eidx,
        const unsigned short* __restrict__ w2t,
        const float* __restrict__ b2, const float* __restrict__ W3, const float* __restrict__ b3,
        float* __restrict__ out)
{
    __shared__ unsigned short sW2[64 * 128];   // XOR-swizzled W2^T
    __shared__ float sB2[64];
    __shared__ float sW3[128];

    const int tid = threadIdx.x, lane = tid & 63, w = tid >> 6;
    const int e16 = lane & 15, g = lane >> 4;

    {   // stage W2^T swizzled (one time)
        int c = tid >> 2, q = tid & 3;
        const unsigned short* src = w2t + c * 128 + q * 32;
#pragma unroll
        for (int i = 0; i < 4; ++i) {
            short8 v = *reinterpret_cast<const short8*>(src + i * 8);
            int chunk = (q * 4 + i) ^ (c & 7);
            *reinterpret_cast<short8*>(&sW2[c * 128 + chunk * 8]) = v;
        }
    }
    if (tid < 64)       sB2[tid] = b2[tid];
    else if (tid < 192) sW3[tid - 64] = W3[tid - 64];
    const float b3v0 = b3[0], b3v1 = b3[1];
    __syncthreads();   // the ONLY barrier; LDS read-only below, waves drift freely

    const int eb = blockIdx.x * EPB + w * 16 + e16;   // this lane's edge for step 0
    G8 bufA, bufB;
    {
        int E = eb; if (E >= E_TOTAL) E = E_TOTAL - 1;
        gather_step(E, eidx, PQ, g, bufA);
    }

#pragma unroll
    for (int s = 0; s < STEPS; s += 2) {
        {   // prefetch step s+1
            int E = eb + (s + 1) * 64; if (E >= E_TOTAL) E = E_TOTAL - 1;
            gather_step(E, eidx, PQ, g, bufB);
        }
        {   // compute step s
            int E = eb + s * 64;
            compute_step(bufA, E, E < E_TOTAL, sW2, sB2, sW3, e16, g, b3v0, b3v1, out);
        }
        if (s + 2 < STEPS) {   // prefetch step s+2
            int E = eb + (s + 2) * 64; if (E >= E_TOTAL) E = E_TOTAL - 1;
            gather_step(E, eidx, PQ, g, bufA);
        }
        {   // compute step s+1
            int E = eb + (s + 1) * 64;
            compute_step(bufB, E, E < E_TOTAL, sW2, sB2, sW3, e16, g, b3v0, b3v1, out);
        }
    }
}

// ============================ HOST ============================

extern "C" void kernel_launch(void* const* d_in, const int* in_sizes, int n_in,
                              void* d_out, int out_size, void* d_ws, size_t ws_size,
                              hipStream_t stream) {
    const float* enc = (const float*)d_in[0];
    const int*   eidx = (const int*)d_in[1];
    const float* W1 = (const float*)d_in[2];
    const float* b1 = (const float*)d_in[3];
    const float* W2 = (const float*)d_in[4];
    const float* b2 = (const float*)d_in[5];
    const float* W3 = (const float*)d_in[6];
    const float* b3 = (const float*)d_in[7];
    float* out = (float*)d_out;

    unsigned short* PQ    = (unsigned short*)d_ws;           // 100000*256 bf16 = 51.2 MB
    unsigned short* w1abt = PQ + (size_t)N_NODES * 256;      // 64 KB
    unsigned short* w2t   = w1abt + 256 * 128;               // 16 KB

    prep_w_fast<<<160, 256, 0, stream>>>(W1, W2, w1abt, w2t);
    build_pq<<<(N_NODES + 63) / 64, 256, 0, stream>>>(enc, b1, w1abt, PQ);
    edge_head2<<<NB, 256, 0, stream>>>(PQ, eidx, w2t, b2, W3, b3, out);
}